// Round 1
// baseline (22810.838 us; speedup 1.0000x reference)
//
#include <hip/hip_runtime.h>
#include <math.h>

#define T_STEPS 4096
#define HID     2048
#define MOD     256
#define INSZ    1024

#define NBLK 32          // blocks in recurrence kernel
#define NTHR 1024        // threads per block (16 waves)
#define RPM  8           // rest rows per module owned by each block
#define NCE  8           // C entries owned by each block

// ---------------------------------------------------------------------------
// Agent-scope (device-coherent) helpers: serviced at the LLC, bypassing the
// non-coherent per-XCD L2s. Packets are self-validating (tag<<32 | fp32 bits)
// so relaxed ordering is sufficient.
// ---------------------------------------------------------------------------
static __device__ __forceinline__ unsigned long long agent_load_u64(
        const unsigned long long* p) {
    return __hip_atomic_load((unsigned long long*)p, __ATOMIC_RELAXED,
                             __HIP_MEMORY_SCOPE_AGENT);
}
static __device__ __forceinline__ void agent_store_u64(
        unsigned long long* p, unsigned long long v) {
    __hip_atomic_store(p, v, __ATOMIC_RELAXED, __HIP_MEMORY_SCOPE_AGENT);
}

// ---------------------------------------------------------------------------
// Kernel 1 (unchanged): U = x @ W_ih^T + (b_ih + b_hh) into out[t, i].
// ---------------------------------------------------------------------------
#define BM 128
#define BN 128
#define BK 8

__global__ __launch_bounds__(256) void gemm_u(
    const float* __restrict__ x, const float* __restrict__ Wih,
    const float* __restrict__ bih, const float* __restrict__ bhh,
    float* __restrict__ out)
{
    __shared__ float As[BK][BM];
    __shared__ float Bs[BK][BN];

    const int tid = threadIdx.x;
    const int t0 = blockIdx.y * BM;
    const int i0 = blockIdx.x * BN;
    const int tx = tid & 15;
    const int ty = tid >> 4;
    const int arow = tid >> 1;
    const int acol = (tid & 1) * 4;

    float acc[8][8];
#pragma unroll
    for (int a = 0; a < 8; ++a)
#pragma unroll
        for (int b = 0; b < 8; ++b) acc[a][b] = 0.0f;

    for (int k0 = 0; k0 < INSZ; k0 += BK) {
        float4 av = *(const float4*)(x   + (size_t)(t0 + arow) * INSZ + k0 + acol);
        float4 bv = *(const float4*)(Wih + (size_t)(i0 + arow) * INSZ + k0 + acol);
        __syncthreads();
        As[acol + 0][arow] = av.x; As[acol + 1][arow] = av.y;
        As[acol + 2][arow] = av.z; As[acol + 3][arow] = av.w;
        Bs[acol + 0][arow] = bv.x; Bs[acol + 1][arow] = bv.y;
        Bs[acol + 2][arow] = bv.z; Bs[acol + 3][arow] = bv.w;
        __syncthreads();
#pragma unroll
        for (int kk = 0; kk < BK; ++kk) {
            float a[8], b[8];
            *(float4*)&a[0] = *(const float4*)&As[kk][ty * 8];
            *(float4*)&a[4] = *(const float4*)&As[kk][ty * 8 + 4];
            *(float4*)&b[0] = *(const float4*)&Bs[kk][tx * 8];
            *(float4*)&b[4] = *(const float4*)&Bs[kk][tx * 8 + 4];
#pragma unroll
            for (int ri = 0; ri < 8; ++ri)
#pragma unroll
                for (int ci = 0; ci < 8; ++ci)
                    acc[ri][ci] = fmaf(a[ri], b[ci], acc[ri][ci]);
        }
    }

    float bias[8];
#pragma unroll
    for (int ci = 0; ci < 8; ++ci) {
        int i = i0 + tx * 8 + ci;
        bias[ci] = bih[i] + bhh[i];
    }
#pragma unroll
    for (int ri = 0; ri < 8; ++ri) {
        int t = t0 + ty * 8 + ri;
#pragma unroll
        for (int ci = 0; ci < 8; ++ci) {
            int i = i0 + tx * 8 + ci;
            out[(size_t)t * HID + i] = acc[ri][ci] + bias[ci];
        }
    }
}

// ---------------------------------------------------------------------------
// Kernel 2: replicated-module-0 recurrence.
//
// 32 blocks x 1024 threads. Every block keeps the FULL h in LDS and W00
// (256x256) in registers (64 VGPR/thread), and recomputes module 0 locally
// every step => odd steps have ZERO cross-block communication. The module-0
// pre-activation uses a cached C[r] = W_hh[r,256:2048] . h_rest, updated
// incrementally at even steps:
//   even step s: each block computes its 8 owned rows of each active rest
//   module (full 2048-dot) and publishes tagged packets; all blocks poll the
//   changed values, form delta = new - old, update replicated h; each block
//   computes its 8 owned entries of C via dC[i] = sum W[i][c]*delta[c] and
//   publishes updated C packets (tag s).
//   odd step t: after the local W00 MAC, blocks poll C packets (tag t-1);
//   the LLC round trip hides under the ~500-cycle MAC.
// Single-slot packet buffers are safe by induction: a producer can only
// overwrite a slot after every block consumed the previous value (the C/dh
// exchanges mutually gate all blocks, skew < 2.5 steps).
//
// out rows double as U storage (gemm output). h(t) is emitted to out row t-1
// with a 2-step delay through a 3-deep LDS ring (64-col slice per block), so
// U prefetches (reader at step t reads row t) always complete before the
// emission (writer at step t+3) can touch the row, given skew < 2.5.
// ---------------------------------------------------------------------------
__global__ __launch_bounds__(NTHR, 4) void cwrnn_rec(
    float* __restrict__ out, const float* __restrict__ Whh,
    unsigned long long* __restrict__ comm)
{
    const int tid   = threadIdx.x;
    const int b     = blockIdx.x;        // 0..31
    const int lane  = tid & 63;
    const int wave  = tid >> 6;          // 0..15
    const int r4    = tid >> 4;          // row group: rows 4*r4..4*r4+3
    const int c16   = tid & 15;          // col group: cols 16*c16..16*c16+15
    const int rsel  = c16 & 3;
    const int myrow = 4 * r4 + rsel;     // row this thread finalizes

    unsigned long long* comm_h = comm;            // [7*256] rest-row packets
    unsigned long long* comm_c = comm + 7 * MOD;  // [256]   C packets

    __shared__ __align__(16) float lds_h[HID];       // replicated full h
    __shared__ __align__(16) float h0p[320];         // padded h0: word = e + (e>>4)*4
    __shared__ __align__(16) float lds_C[MOD];       // replicated C
    __shared__ __align__(16) float lds_delta[7 * MOD];
    __shared__ __align__(16) float lds_u0[MOD];      // U0[t] (prefetched)
    __shared__ __align__(16) float lds_ur[56];       // U[t] for owned rest rows
    __shared__ __align__(16) float lds_ring[3][64];  // delayed out slice
    __shared__ float lds_red[NCE][2];

    // ---- W00 fragment in registers: rows 4r4..+3, cols 16c16..+15
    float4 w00[4][4];
#pragma unroll
    for (int rr = 0; rr < 4; ++rr) {
        const float* wr = Whh + (size_t)(4 * r4 + rr) * HID + 16 * c16;
#pragma unroll
        for (int i = 0; i < 4; ++i) w00[rr][i] = *(const float4*)(wr + 4 * i);
    }

    // ---- zero init (h(0) = 0, C(0) = 0)
    for (int i = tid; i < HID; i += NTHR) lds_h[i] = 0.f;
    if (tid < 320) h0p[tid] = 0.f;
    if (tid < MOD) lds_C[tid] = 0.f;
    if (tid < 56)  lds_ur[tid] = 0.f;
    if (tid < 192) (&lds_ring[0][0])[tid] = 0.f;

    {   // preload U(1) = gemm row 0, cols [0,256)
        float4 u4 = make_float4(0.f, 0.f, 0.f, 0.f);
        if (tid < 64) u4 = *(const float4*)(out + 4 * tid);
        __syncthreads();
        if (tid < 64) *(float4*)(lds_u0 + 4 * tid) = u4;
        __syncthreads();
    }

    for (int t = 1; t <= T_STEPS; ++t) {
        const bool ev = (t & 1) == 0;
        const int ctz = __builtin_ctz(t);
        const int j   = ev ? (ctz < 7 ? ctz : 7) : 0;  // active rest modules 1..j
        const unsigned long long tagbits =
            ((unsigned long long)(unsigned)t) << 32;

        // ---------- early phase: U value, delayed emission, U prefetch issue
        const float uval = lds_u0[myrow];
        if (t >= 3 && tid < 16) {   // emit out row t-3 = h(t-2), slot (t-2)%3
            float4 e4 = *(const float4*)(&lds_ring[(t + 1) % 3][4 * tid]);
            *(float4*)(out + (size_t)(t - 3) * HID + 64 * b + 4 * tid) = e4;
        }
        float4 pf0 = make_float4(0.f, 0.f, 0.f, 0.f);
        float4 pfr = make_float4(0.f, 0.f, 0.f, 0.f);
        if (t < T_STEPS) {
            if (tid < 64)   // U0 for step t+1 (gemm row t)
                pf0 = *(const float4*)(out + (size_t)t * HID + 4 * tid);
            if (!ev && tid >= 64 && tid < 78) {  // rest-U for even step t+1
                const int idx = tid - 64, mm = idx >> 1, dd = idx & 1;
                pfr = *(const float4*)(out + (size_t)t * HID
                                       + (mm + 1) * MOD + RPM * b + 4 * dd);
            }
        }

        // ---------- even: owned rest rows (full 2048-dot) + publish
        if (ev) {
            for (int ridx = wave; ridx < RPM * j; ridx += 16) {
                const int m = 1 + (ridx >> 3);
                const int e = ridx & 7;
                const float* wrow = Whh + (size_t)(m * MOD + RPM * b + e) * HID;
                float4 wv[8];
#pragma unroll
                for (int k = 0; k < 8; ++k)
                    wv[k] = *(const float4*)(wrow + 4 * lane + 256 * k);
                float sx = 0.f, sy = 0.f, sz = 0.f, sw = 0.f;
#pragma unroll
                for (int k = 0; k < 8; ++k) {
                    const float4 hv = *(const float4*)(lds_h + 4 * lane + 256 * k);
                    sx = fmaf(wv[k].x, hv.x, sx);
                    sy = fmaf(wv[k].y, hv.y, sy);
                    sz = fmaf(wv[k].z, hv.z, sz);
                    sw = fmaf(wv[k].w, hv.w, sw);
                }
                float acc = (sx + sy) + (sz + sw);
#pragma unroll
                for (int off = 32; off; off >>= 1)
                    acc += __shfl_xor(acc, off, 64);
                if (lane == 0) {
                    const float hv = tanhf(lds_ur[(m - 1) * 8 + e] + acc);
                    agent_store_u64(comm_h + (m - 1) * MOD + RPM * b + e,
                        tagbits | (unsigned long long)__float_as_uint(hv));
                }
            }
        }

        // ---------- module-0 MAC (every step, fully local): W00 . h0(t-1)
        float a0 = 0.f, a1 = 0.f, a2 = 0.f, a3 = 0.f;
#pragma unroll
        for (int i = 0; i < 4; ++i) {
            const float4 hv = *(const float4*)(h0p + 20 * c16 + 4 * i);
            a0 = fmaf(w00[0][i].x, hv.x, a0); a0 = fmaf(w00[0][i].y, hv.y, a0);
            a0 = fmaf(w00[0][i].z, hv.z, a0); a0 = fmaf(w00[0][i].w, hv.w, a0);
            a1 = fmaf(w00[1][i].x, hv.x, a1); a1 = fmaf(w00[1][i].y, hv.y, a1);
            a1 = fmaf(w00[1][i].z, hv.z, a1); a1 = fmaf(w00[1][i].w, hv.w, a1);
            a2 = fmaf(w00[2][i].x, hv.x, a2); a2 = fmaf(w00[2][i].y, hv.y, a2);
            a2 = fmaf(w00[2][i].z, hv.z, a2); a2 = fmaf(w00[2][i].w, hv.w, a2);
            a3 = fmaf(w00[3][i].x, hv.x, a3); a3 = fmaf(w00[3][i].y, hv.y, a3);
            a3 = fmaf(w00[3][i].z, hv.z, a3); a3 = fmaf(w00[3][i].w, hv.w, a3);
        }
#pragma unroll
        for (int off = 1; off <= 8; off <<= 1) {  // reduce over the 16 c16 lanes
            a0 += __shfl_xor(a0, off, 64);
            a1 += __shfl_xor(a1, off, 64);
            a2 += __shfl_xor(a2, off, 64);
            a3 += __shfl_xor(a3, off, 64);
        }
        const float pre = (rsel == 0) ? a0 : (rsel == 1) ? a1
                        : (rsel == 2) ? a2 : a3;

        if (!ev) {
            // ---- odd: poll C (tag t-1; t=1 passes on memset tags==0)
            if (tid < MOD) {
                const unsigned need = (unsigned)(t - 1);
                unsigned long long pv;
                do { pv = agent_load_u64(comm_c + tid); }
                while ((unsigned)(pv >> 32) < need);
                lds_C[tid] = __uint_as_float((unsigned)pv);
            }
            __syncthreads();                                   // A
            const float hv_new = tanhf(uval + lds_C[myrow] + pre);
            if (c16 < 4) {
                lds_h[myrow] = hv_new;
                h0p[myrow + (myrow >> 4) * 4] = hv_new;
                if (b < 4 && (myrow >> 6) == b)
                    lds_ring[t % 3][myrow & 63] = hv_new;
            }
            if (b >= 4 && tid < 16)   // slice unchanged at odd steps: carry
                *(float4*)(&lds_ring[t % 3][4 * tid]) =
                    *(const float4*)(&lds_ring[(t + 2) % 3][4 * tid]);
            if (t < T_STEPS) {
                if (tid < 64) *(float4*)(lds_u0 + 4 * tid) = pf0;
                if (tid >= 64 && tid < 78) {
                    const int idx = tid - 64;
                    *(float4*)(lds_ur + (idx >> 1) * 8 + 4 * (idx & 1)) = pfr;
                }
            }
            __syncthreads();                                   // B (end)
        } else {
            // ---- even: finish module-0 with the CURRENT C (vintage s-2)
            const float hv_new = tanhf(uval + lds_C[myrow] + pre);
            __syncthreads();                                   // A
            if (c16 < 4) {
                lds_h[myrow] = hv_new;
                h0p[myrow + (myrow >> 4) * 4] = hv_new;
                if (b < 4 && (myrow >> 6) == b)
                    lds_ring[t % 3][myrow & 63] = hv_new;
            }
            // ---- poll changed rest modules (tag t), update h + delta
            const int nslot = j * MOD;
            {
                const unsigned need = (unsigned)t;
                const int s0 = tid, s1 = tid + NTHR;
                const bool w0 = s0 < nslot, w1 = s1 < nslot;
                unsigned long long p0 = 0, p1 = 0;
                if (w0 | w1) {
                    for (;;) {
                        if (w0) p0 = agent_load_u64(comm_h + s0);
                        if (w1) p1 = agent_load_u64(comm_h + s1);
                        if ((!w0 || (unsigned)(p0 >> 32) >= need) &&
                            (!w1 || (unsigned)(p1 >> 32) >= need)) break;
                    }
                }
                const int base = 64 * b - MOD;   // slice slot base (b>=4)
                if (w0) {
                    const float v = __uint_as_float((unsigned)p0);
                    lds_delta[s0] = v - lds_h[MOD + s0];
                    lds_h[MOD + s0] = v;
                    if (b >= 4 && s0 >= base && s0 < base + 64)
                        lds_ring[t % 3][s0 - base] = v;
                }
                if (w1) {
                    const float v = __uint_as_float((unsigned)p1);
                    lds_delta[s1] = v - lds_h[MOD + s1];
                    lds_h[MOD + s1] = v;
                    if (b >= 4 && s1 >= base && s1 < base + 64)
                        lds_ring[t % 3][s1 - base] = v;
                }
            }
            if (b >= 4 && (b >> 2) > j && tid < 16)  // slice module inactive
                *(float4*)(&lds_ring[t % 3][4 * tid]) =
                    *(const float4*)(&lds_ring[(t + 2) % 3][4 * tid]);
            if (t < T_STEPS && tid < 64)
                *(float4*)(lds_u0 + 4 * tid) = pf0;
            __syncthreads();                                   // B
            // ---- owned dC entries + publish updated C (tag t)
            {
                const int e   = tid >> 7;          // 0..7
                const int sub = tid & 127;
                const float* wc = Whh + (size_t)(NCE * b + e) * HID + MOD;
                float acc = 0.f;
                for (int kk = sub; kk < nslot; kk += 128)
                    acc = fmaf(wc[kk], lds_delta[kk], acc);
#pragma unroll
                for (int off = 32; off; off >>= 1)
                    acc += __shfl_xor(acc, off, 64);
                if (lane == 0) lds_red[e][(tid >> 6) & 1] = acc;
            }
            __syncthreads();                                   // C
            if (tid < NCE) {
                const int gi = NCE * b + tid;
                const float cn = lds_C[gi] + lds_red[tid][0] + lds_red[tid][1];
                agent_store_u64(comm_c + gi,
                    tagbits | (unsigned long long)__float_as_uint(cn));
            }
            // no barrier needed: lds_red untouched until after next even B
        }
    }

    // ---- flush the last two delayed rows: h(T-1) -> row T-2, h(T) -> row T-1
    __syncthreads();
    if (tid < 16) {
        *(float4*)(out + (size_t)(T_STEPS - 2) * HID + 64 * b + 4 * tid) =
            *(const float4*)(&lds_ring[(T_STEPS - 1) % 3][4 * tid]);
        *(float4*)(out + (size_t)(T_STEPS - 1) * HID + 64 * b + 4 * tid) =
            *(const float4*)(&lds_ring[T_STEPS % 3][4 * tid]);
    }
}

// ---------------------------------------------------------------------------
extern "C" void kernel_launch(void* const* d_in, const int* in_sizes, int n_in,
                              void* d_out, int out_size, void* d_ws, size_t ws_size,
                              hipStream_t stream) {
    const float* x   = (const float*)d_in[0];
    const float* Wih = (const float*)d_in[1];
    const float* Whh = (const float*)d_in[2];
    const float* bih = (const float*)d_in[3];
    const float* bhh = (const float*)d_in[4];
    float* out = (float*)d_out;
    unsigned long long* comm = (unsigned long long*)d_ws;

    // packet tags must start at 0 (t runs 1..4096): (1792 + 256) x 8B = 16 KB
    hipMemsetAsync(d_ws, 0, (7 * MOD + MOD) * sizeof(unsigned long long), stream);

    dim3 g1(HID / BN, T_STEPS / BM);        // (16, 32)
    gemm_u<<<g1, 256, 0, stream>>>(x, Wih, bih, bhh, out);
    cwrnn_rec<<<NBLK, NTHR, 0, stream>>>(out, Whh, comm);
}

// Round 2
// 15105.190 us; speedup vs baseline: 1.5101x; 1.5101x over previous
//
#include <hip/hip_runtime.h>
#include <math.h>

#define T_STEPS 4096
#define HID     2048
#define MOD     256
#define INSZ    1024

#define NBLK 32          // blocks in recurrence kernel
#define NTHR 512         // threads per block (8 waves = 2 waves/SIMD -> 256 VGPR)
#define RPM  8           // rest rows per module owned by each block
#define NCE  8           // C entries owned by each block

// ---------------------------------------------------------------------------
// Agent-scope (device-coherent) helpers: serviced at the LLC, bypassing the
// non-coherent per-XCD L2s. Packets are self-validating (tag<<32 | fp32 bits)
// so relaxed ordering is sufficient.
// ---------------------------------------------------------------------------
static __device__ __forceinline__ unsigned long long agent_load_u64(
        const unsigned long long* p) {
    return __hip_atomic_load((unsigned long long*)p, __ATOMIC_RELAXED,
                             __HIP_MEMORY_SCOPE_AGENT);
}
static __device__ __forceinline__ void agent_store_u64(
        unsigned long long* p, unsigned long long v) {
    __hip_atomic_store(p, v, __ATOMIC_RELAXED, __HIP_MEMORY_SCOPE_AGENT);
}

// ---------------------------------------------------------------------------
// Kernel 1 (unchanged): U = x @ W_ih^T + (b_ih + b_hh) into out[t, i].
// ---------------------------------------------------------------------------
#define BM 128
#define BN 128
#define BK 8

__global__ __launch_bounds__(256) void gemm_u(
    const float* __restrict__ x, const float* __restrict__ Wih,
    const float* __restrict__ bih, const float* __restrict__ bhh,
    float* __restrict__ out)
{
    __shared__ float As[BK][BM];
    __shared__ float Bs[BK][BN];

    const int tid = threadIdx.x;
    const int t0 = blockIdx.y * BM;
    const int i0 = blockIdx.x * BN;
    const int tx = tid & 15;
    const int ty = tid >> 4;
    const int arow = tid >> 1;
    const int acol = (tid & 1) * 4;

    float acc[8][8];
#pragma unroll
    for (int a = 0; a < 8; ++a)
#pragma unroll
        for (int b = 0; b < 8; ++b) acc[a][b] = 0.0f;

    for (int k0 = 0; k0 < INSZ; k0 += BK) {
        float4 av = *(const float4*)(x   + (size_t)(t0 + arow) * INSZ + k0 + acol);
        float4 bv = *(const float4*)(Wih + (size_t)(i0 + arow) * INSZ + k0 + acol);
        __syncthreads();
        As[acol + 0][arow] = av.x; As[acol + 1][arow] = av.y;
        As[acol + 2][arow] = av.z; As[acol + 3][arow] = av.w;
        Bs[acol + 0][arow] = bv.x; Bs[acol + 1][arow] = bv.y;
        Bs[acol + 2][arow] = bv.z; Bs[acol + 3][arow] = bv.w;
        __syncthreads();
#pragma unroll
        for (int kk = 0; kk < BK; ++kk) {
            float a[8], b[8];
            *(float4*)&a[0] = *(const float4*)&As[kk][ty * 8];
            *(float4*)&a[4] = *(const float4*)&As[kk][ty * 8 + 4];
            *(float4*)&b[0] = *(const float4*)&Bs[kk][tx * 8];
            *(float4*)&b[4] = *(const float4*)&Bs[kk][tx * 8 + 4];
#pragma unroll
            for (int ri = 0; ri < 8; ++ri)
#pragma unroll
                for (int ci = 0; ci < 8; ++ci)
                    acc[ri][ci] = fmaf(a[ri], b[ci], acc[ri][ci]);
        }
    }

    float bias[8];
#pragma unroll
    for (int ci = 0; ci < 8; ++ci) {
        int i = i0 + tx * 8 + ci;
        bias[ci] = bih[i] + bhh[i];
    }
#pragma unroll
    for (int ri = 0; ri < 8; ++ri) {
        int t = t0 + ty * 8 + ri;
#pragma unroll
        for (int ci = 0; ci < 8; ++ci) {
            int i = i0 + tx * 8 + ci;
            out[(size_t)t * HID + i] = acc[ri][ci] + bias[ci];
        }
    }
}

// ---------------------------------------------------------------------------
// Kernel 2: replicated-module-0 recurrence. 32 blocks x 512 threads.
//
// Every block keeps the FULL h in LDS and W00 (256x256) in REGISTERS
// (128 VGPR/thread: 8 rows x 16 cols), and recomputes module 0 locally every
// step => odd steps have ZERO cross-block communication. Module-0 uses a
// cached C[r] = W_hh[r,256:2048] . h_rest, updated incrementally at even
// steps via delta packets. Poll loads are ISSUED BEFORE the W00 MAC so the
// LLC round trip hides under ~400 cycles of local compute.
//
// Single-slot packet buffers are safe by induction (skew < 2.5 steps): a
// producer can only advance past an exchange after every block consumed the
// previous vintage (true data dependency through the C/dh packets).
//
// out rows double as U storage (gemm output). h(t) is emitted to out row t-3
// through a 3-deep LDS ring (64-col slice per block), so U prefetches (reader
// at step t reads row t) always complete before any writer touches the row.
// ---------------------------------------------------------------------------
__global__ __launch_bounds__(NTHR, 1) void cwrnn_rec(
    float* __restrict__ out, const float* __restrict__ Whh,
    unsigned long long* __restrict__ comm)
{
    const int tid   = threadIdx.x;
    const int b     = blockIdx.x;        // 0..31
    const int lane  = tid & 63;
    const int wave  = tid >> 6;          // 0..7
    const int r8    = tid >> 4;          // row group: rows 8*r8..8*r8+7
    const int c16   = tid & 15;          // col group: cols 16*c16..16*c16+15
    const int rsel  = c16 & 7;
    const int myrow = 8 * r8 + rsel;     // row this thread finalizes (c16<8)

    unsigned long long* comm_h = comm;            // [7*256] rest-row packets
    unsigned long long* comm_c = comm + 7 * MOD;  // [256]   C packets

    __shared__ __align__(16) float lds_h[HID];       // replicated full h
    __shared__ __align__(16) float h0p[320];         // padded h0: word = e + (e>>4)*4
    __shared__ __align__(16) float lds_C[MOD];       // replicated C
    __shared__ __align__(16) float lds_delta[7 * MOD];
    __shared__ __align__(16) float lds_u0[MOD];      // U0[t] (prefetched)
    __shared__ __align__(16) float lds_ur[56];       // U[t] for owned rest rows
    __shared__ __align__(16) float lds_ring[3][64];  // delayed out slice

    // ---- W00 fragment in registers: rows 8r8..+7, cols 16c16..+15 (128 VGPR)
    float4 w00[8][4];
#pragma unroll
    for (int rr = 0; rr < 8; ++rr) {
        const float* wr = Whh + (size_t)(8 * r8 + rr) * HID + 16 * c16;
#pragma unroll
        for (int i = 0; i < 4; ++i) w00[rr][i] = *(const float4*)(wr + 4 * i);
    }

    // ---- zero init (h(0) = 0, C(0) = 0)
    for (int i = tid; i < HID; i += NTHR) lds_h[i] = 0.f;
    if (tid < 320) h0p[tid] = 0.f;
    if (tid < MOD) lds_C[tid] = 0.f;
    if (tid < 56)  lds_ur[tid] = 0.f;
    if (tid < 192) (&lds_ring[0][0])[tid] = 0.f;

    {   // preload U(1) = gemm row 0, cols [0,256)
        float4 u4 = make_float4(0.f, 0.f, 0.f, 0.f);
        if (tid < 64) u4 = *(const float4*)(out + 4 * tid);
        __syncthreads();
        if (tid < 64) *(float4*)(lds_u0 + 4 * tid) = u4;
        __syncthreads();
    }

    for (int t = 1; t <= T_STEPS; ++t) {
        const bool ev = (t & 1) == 0;
        const int ctz = __builtin_ctz(t);
        const int j   = ev ? (ctz < 7 ? ctz : 7) : 0;  // active rest modules 1..j
        const unsigned long long tagbits =
            ((unsigned long long)(unsigned)t) << 32;

        // ---------- early phase: U value, delayed emission, U prefetch issue
        const float uval = lds_u0[myrow];
        if (t >= 3 && tid < 16) {   // emit out row t-3 = h(t-2), slot (t+1)%3
            float4 e4 = *(const float4*)(&lds_ring[(t + 1) % 3][4 * tid]);
            *(float4*)(out + (size_t)(t - 3) * HID + 64 * b + 4 * tid) = e4;
        }
        float4 pf0 = make_float4(0.f, 0.f, 0.f, 0.f);
        float4 pfr = make_float4(0.f, 0.f, 0.f, 0.f);
        if (t < T_STEPS) {
            if (tid < 64)   // U0 for step t+1 (gemm row t)
                pf0 = *(const float4*)(out + (size_t)t * HID + 4 * tid);
            if (!ev && tid >= 64 && tid < 78) {  // rest-U for even step t+1
                const int idx = tid - 64, mm = idx >> 1, dd = idx & 1;
                pfr = *(const float4*)(out + (size_t)t * HID
                                       + (mm + 1) * MOD + RPM * b + 4 * dd);
            }
        }

        // ---------- even: owned rest rows (full 2048-dot) + publish
        if (ev) {
            for (int ridx = wave; ridx < RPM * j; ridx += 8) {
                const int m = 1 + (ridx >> 3);
                const int e = ridx & 7;
                const float* wrow = Whh + (size_t)(m * MOD + RPM * b + e) * HID;
                float4 wv[8];
#pragma unroll
                for (int k = 0; k < 8; ++k)
                    wv[k] = *(const float4*)(wrow + 4 * lane + 256 * k);
                float sx = 0.f, sy = 0.f, sz = 0.f, sw = 0.f;
#pragma unroll
                for (int k = 0; k < 8; ++k) {
                    const float4 hv = *(const float4*)(lds_h + 4 * lane + 256 * k);
                    sx = fmaf(wv[k].x, hv.x, sx);
                    sy = fmaf(wv[k].y, hv.y, sy);
                    sz = fmaf(wv[k].z, hv.z, sz);
                    sw = fmaf(wv[k].w, hv.w, sw);
                }
                float acc = (sx + sy) + (sz + sw);
#pragma unroll
                for (int off = 32; off; off >>= 1)
                    acc += __shfl_xor(acc, off, 64);
                if (lane == 0) {
                    const float hv = tanhf(lds_ur[(m - 1) * 8 + e] + acc);
                    agent_store_u64(comm_h + (m - 1) * MOD + RPM * b + e,
                        tagbits | (unsigned long long)__float_as_uint(hv));
                }
            }
        }

        // ---------- issue poll prefetch loads (hidden under the W00 MAC)
        const int nslot = j * MOD;
        unsigned long long hp0 = 0, hp1 = 0, hp2 = 0, hp3 = 0;
        const bool hw0 = ev && (tid < nslot);
        const bool hw1 = ev && (tid + 512 < nslot);
        const bool hw2 = ev && (tid + 1024 < nslot);
        const bool hw3 = ev && (tid + 1536 < nslot);
        unsigned long long cp = 0;
        if (ev) {
            if (hw0) hp0 = agent_load_u64(comm_h + tid);
            if (hw1) hp1 = agent_load_u64(comm_h + tid + 512);
            if (hw2) hp2 = agent_load_u64(comm_h + tid + 1024);
            if (hw3) hp3 = agent_load_u64(comm_h + tid + 1536);
        } else {
            if (tid < MOD) cp = agent_load_u64(comm_c + tid);
        }

        // ---------- module-0 MAC (every step, fully local): W00 . h0(t-1)
        float a[8];
#pragma unroll
        for (int rr = 0; rr < 8; ++rr) a[rr] = 0.f;
#pragma unroll
        for (int i = 0; i < 4; ++i) {
            const float4 hv = *(const float4*)(h0p + 20 * c16 + 4 * i);
#pragma unroll
            for (int rr = 0; rr < 8; ++rr) {
                a[rr] = fmaf(w00[rr][i].x, hv.x, a[rr]);
                a[rr] = fmaf(w00[rr][i].y, hv.y, a[rr]);
                a[rr] = fmaf(w00[rr][i].z, hv.z, a[rr]);
                a[rr] = fmaf(w00[rr][i].w, hv.w, a[rr]);
            }
        }
#pragma unroll
        for (int off = 1; off <= 8; off <<= 1) {
#pragma unroll
            for (int rr = 0; rr < 8; ++rr)
                a[rr] += __shfl_xor(a[rr], off, 64);
        }
        float pre = a[0];                    // static-index select (rule #20)
#pragma unroll
        for (int rr = 1; rr < 8; ++rr) pre = (rsel == rr) ? a[rr] : pre;

        if (!ev) {
            // ---- odd: finish C poll (tag t-1; t=1 passes on memset tags==0)
            if (tid < MOD) {
                const unsigned need = (unsigned)(t - 1);
                while ((unsigned)(cp >> 32) < need)
                    cp = agent_load_u64(comm_c + tid);
            }
            __syncthreads();                                   // A (GEMV-free step: orders lds_C)
            if (tid < MOD) lds_C[tid] = __uint_as_float((unsigned)cp);
            __syncthreads();                                   // A'
            const float hv_new = tanhf(uval + lds_C[myrow] + pre);
            if (c16 < 8) {
                lds_h[myrow] = hv_new;
                h0p[myrow + (myrow >> 4) * 4] = hv_new;
                if (b < 4 && (myrow >> 6) == b)
                    lds_ring[t % 3][myrow & 63] = hv_new;
            }
            if (b >= 4 && tid < 16)   // slice unchanged at odd steps: carry
                *(float4*)(&lds_ring[t % 3][4 * tid]) =
                    *(const float4*)(&lds_ring[(t + 2) % 3][4 * tid]);
            if (t < T_STEPS) {
                if (tid < 64) *(float4*)(lds_u0 + 4 * tid) = pf0;
                if (tid >= 64 && tid < 78) {
                    const int idx = tid - 64;
                    *(float4*)(lds_ur + (idx >> 1) * 8 + 4 * (idx & 1)) = pfr;
                }
            }
            __syncthreads();                                   // B (end)
        } else {
            // ---- even: finish module-0 with the CURRENT C (vintage t-2)
            const float hv_new = tanhf(uval + lds_C[myrow] + pre);
            // ---- finish h-packet poll (tag t), register-only retry
            {
                const unsigned need = (unsigned)t;
                for (;;) {
                    bool ok = (!hw0 || (unsigned)(hp0 >> 32) >= need)
                           && (!hw1 || (unsigned)(hp1 >> 32) >= need)
                           && (!hw2 || (unsigned)(hp2 >> 32) >= need)
                           && (!hw3 || (unsigned)(hp3 >> 32) >= need);
                    if (ok) break;
                    if (hw0) hp0 = agent_load_u64(comm_h + tid);
                    if (hw1) hp1 = agent_load_u64(comm_h + tid + 512);
                    if (hw2) hp2 = agent_load_u64(comm_h + tid + 1024);
                    if (hw3) hp3 = agent_load_u64(comm_h + tid + 1536);
                }
            }
            __syncthreads();                                   // A (all lds_h reads done)
            if (c16 < 8) {
                lds_h[myrow] = hv_new;
                h0p[myrow + (myrow >> 4) * 4] = hv_new;
                if (b < 4 && (myrow >> 6) == b)
                    lds_ring[t % 3][myrow & 63] = hv_new;
            }
            {   // commit polled rest-h values, form deltas, update ring slice
                const int base = 64 * b - MOD;   // slice slot base (b>=4)
                if (hw0) {
                    const float v = __uint_as_float((unsigned)hp0);
                    const int s = tid;
                    lds_delta[s] = v - lds_h[MOD + s];
                    lds_h[MOD + s] = v;
                    if (b >= 4 && s >= base && s < base + 64)
                        lds_ring[t % 3][s - base] = v;
                }
                if (hw1) {
                    const float v = __uint_as_float((unsigned)hp1);
                    const int s = tid + 512;
                    lds_delta[s] = v - lds_h[MOD + s];
                    lds_h[MOD + s] = v;
                    if (b >= 4 && s >= base && s < base + 64)
                        lds_ring[t % 3][s - base] = v;
                }
                if (hw2) {
                    const float v = __uint_as_float((unsigned)hp2);
                    const int s = tid + 1024;
                    lds_delta[s] = v - lds_h[MOD + s];
                    lds_h[MOD + s] = v;
                    if (b >= 4 && s >= base && s < base + 64)
                        lds_ring[t % 3][s - base] = v;
                }
                if (hw3) {
                    const float v = __uint_as_float((unsigned)hp3);
                    const int s = tid + 1536;
                    lds_delta[s] = v - lds_h[MOD + s];
                    lds_h[MOD + s] = v;
                    if (b >= 4 && s >= base && s < base + 64)
                        lds_ring[t % 3][s - base] = v;
                }
            }
            if (b >= 4 && (b >> 2) > j && tid < 16)  // slice module inactive
                *(float4*)(&lds_ring[t % 3][4 * tid]) =
                    *(const float4*)(&lds_ring[(t + 2) % 3][4 * tid]);
            if (t < T_STEPS && tid < 64)
                *(float4*)(lds_u0 + 4 * tid) = pf0;
            __syncthreads();                                   // B
            // ---- owned dC entry (one wave per entry) + publish (tag t).
            // Safe without a trailing barrier: lds_C[gi] is re-written only at
            // the next odd step by thread gi, whose comm_c poll cannot succeed
            // until THIS store lands (self-synchronizing through the packet).
            {
                const float* wc = Whh + (size_t)(NCE * b + wave) * HID + MOD;
                float acc = 0.f;
                for (int k0 = 0; k0 < nslot; k0 += 256) {
                    const float w0_ = wc[k0 + lane];
                    const float w1_ = wc[k0 + lane + 64];
                    const float w2_ = wc[k0 + lane + 128];
                    const float w3_ = wc[k0 + lane + 192];
                    acc = fmaf(w0_, lds_delta[k0 + lane], acc);
                    acc = fmaf(w1_, lds_delta[k0 + lane + 64], acc);
                    acc = fmaf(w2_, lds_delta[k0 + lane + 128], acc);
                    acc = fmaf(w3_, lds_delta[k0 + lane + 192], acc);
                }
#pragma unroll
                for (int off = 32; off; off >>= 1)
                    acc += __shfl_xor(acc, off, 64);
                if (lane == 0) {
                    const int gi = NCE * b + wave;
                    const float cn = lds_C[gi] + acc;
                    agent_store_u64(comm_c + gi,
                        tagbits | (unsigned long long)__float_as_uint(cn));
                }
            }
        }
    }

    // ---- flush the last two delayed rows: h(T-1) -> row T-2, h(T) -> row T-1
    __syncthreads();
    if (tid < 16) {
        *(float4*)(out + (size_t)(T_STEPS - 2) * HID + 64 * b + 4 * tid) =
            *(const float4*)(&lds_ring[(T_STEPS - 1) % 3][4 * tid]);
        *(float4*)(out + (size_t)(T_STEPS - 1) * HID + 64 * b + 4 * tid) =
            *(const float4*)(&lds_ring[T_STEPS % 3][4 * tid]);
    }
}

// ---------------------------------------------------------------------------
extern "C" void kernel_launch(void* const* d_in, const int* in_sizes, int n_in,
                              void* d_out, int out_size, void* d_ws, size_t ws_size,
                              hipStream_t stream) {
    const float* x   = (const float*)d_in[0];
    const float* Wih = (const float*)d_in[1];
    const float* Whh = (const float*)d_in[2];
    const float* bih = (const float*)d_in[3];
    const float* bhh = (const float*)d_in[4];
    float* out = (float*)d_out;
    unsigned long long* comm = (unsigned long long*)d_ws;

    // packet tags must start at 0 (t runs 1..4096): (1792 + 256) x 8B = 16 KB
    hipMemsetAsync(d_ws, 0, (7 * MOD + MOD) * sizeof(unsigned long long), stream);

    dim3 g1(HID / BN, T_STEPS / BM);        // (16, 32)
    gemm_u<<<g1, 256, 0, stream>>>(x, Wih, bih, bhh, out);
    cwrnn_rec<<<NBLK, NTHR, 0, stream>>>(out, Whh, comm);
}

// Round 3
// 14724.710 us; speedup vs baseline: 1.5492x; 1.0258x over previous
//
#include <hip/hip_runtime.h>
#include <math.h>

#define T_STEPS 4096
#define HID     2048
#define MOD     256
#define INSZ    1024

#define NBLK 32          // blocks in recurrence kernel
#define NTHR 512         // threads per block (8 waves = 2 waves/SIMD)
#define RPM  8           // rest rows per module owned by each block
#define NCE  8           // C entries owned by each block

// ---------------------------------------------------------------------------
// Agent-scope (device-coherent) helpers: serviced at the LLC, bypassing the
// non-coherent per-XCD L2s. Packets are self-validating (tag<<32 | fp32 bits)
// so relaxed ordering is sufficient.
// ---------------------------------------------------------------------------
static __device__ __forceinline__ unsigned long long agent_load_u64(
        const unsigned long long* p) {
    return __hip_atomic_load((unsigned long long*)p, __ATOMIC_RELAXED,
                             __HIP_MEMORY_SCOPE_AGENT);
}
static __device__ __forceinline__ void agent_store_u64(
        unsigned long long* p, unsigned long long v) {
    __hip_atomic_store(p, v, __ATOMIC_RELAXED, __HIP_MEMORY_SCOPE_AGENT);
}

// ---------------------------------------------------------------------------
// Kernel 1 (unchanged): U = x @ W_ih^T + (b_ih + b_hh) into out[t, i].
// ---------------------------------------------------------------------------
#define BM 128
#define BN 128
#define BK 8

__global__ __launch_bounds__(256) void gemm_u(
    const float* __restrict__ x, const float* __restrict__ Wih,
    const float* __restrict__ bih, const float* __restrict__ bhh,
    float* __restrict__ out)
{
    __shared__ float As[BK][BM];
    __shared__ float Bs[BK][BN];

    const int tid = threadIdx.x;
    const int t0 = blockIdx.y * BM;
    const int i0 = blockIdx.x * BN;
    const int tx = tid & 15;
    const int ty = tid >> 4;
    const int arow = tid >> 1;
    const int acol = (tid & 1) * 4;

    float acc[8][8];
#pragma unroll
    for (int a = 0; a < 8; ++a)
#pragma unroll
        for (int b = 0; b < 8; ++b) acc[a][b] = 0.0f;

    for (int k0 = 0; k0 < INSZ; k0 += BK) {
        float4 av = *(const float4*)(x   + (size_t)(t0 + arow) * INSZ + k0 + acol);
        float4 bv = *(const float4*)(Wih + (size_t)(i0 + arow) * INSZ + k0 + acol);
        __syncthreads();
        As[acol + 0][arow] = av.x; As[acol + 1][arow] = av.y;
        As[acol + 2][arow] = av.z; As[acol + 3][arow] = av.w;
        Bs[acol + 0][arow] = bv.x; Bs[acol + 1][arow] = bv.y;
        Bs[acol + 2][arow] = bv.z; Bs[acol + 3][arow] = bv.w;
        __syncthreads();
#pragma unroll
        for (int kk = 0; kk < BK; ++kk) {
            float a[8], b[8];
            *(float4*)&a[0] = *(const float4*)&As[kk][ty * 8];
            *(float4*)&a[4] = *(const float4*)&As[kk][ty * 8 + 4];
            *(float4*)&b[0] = *(const float4*)&Bs[kk][tx * 8];
            *(float4*)&b[4] = *(const float4*)&Bs[kk][tx * 8 + 4];
#pragma unroll
            for (int ri = 0; ri < 8; ++ri)
#pragma unroll
                for (int ci = 0; ci < 8; ++ci)
                    acc[ri][ci] = fmaf(a[ri], b[ci], acc[ri][ci]);
        }
    }

    float bias[8];
#pragma unroll
    for (int ci = 0; ci < 8; ++ci) {
        int i = i0 + tx * 8 + ci;
        bias[ci] = bih[i] + bhh[i];
    }
#pragma unroll
    for (int ri = 0; ri < 8; ++ri) {
        int t = t0 + ty * 8 + ri;
#pragma unroll
        for (int ci = 0; ci < 8; ++ci) {
            int i = i0 + tx * 8 + ci;
            out[(size_t)t * HID + i] = acc[ri][ci] + bias[ci];
        }
    }
}

// ---------------------------------------------------------------------------
// Kernel 2: replicated-module-0 recurrence. 32 blocks x 512 threads.
//
// amdgpu_waves_per_eu(2,2): pins the compiler's occupancy target to 2
// waves/EU (1 block/CU) => 256-VGPR budget, so the W00 register cache
// (128 VGPR/thread) is NOT spilled. launch_bounds' 2nd arg alone only sets
// the MINIMUM waves/EU; r1/r2 showed the compiler then targets 4 waves/EU
// (128 VGPR) and spills W00 to scratch.
//
// Every block keeps the FULL h in LDS and W00 (256x256) in REGISTERS
// (128 VGPR/thread: 8 rows x 16 cols), and recomputes module 0 locally every
// step => odd steps have ZERO cross-block communication. Module-0 uses a
// cached C[r] = W_hh[r,256:2048] . h_rest, updated incrementally at even
// steps via delta packets. Poll loads are ISSUED BEFORE the W00 MAC so the
// LLC round trip hides under local compute.
//
// Single-slot packet buffers are safe by induction (skew < 2.5 steps): a
// producer can only advance past an exchange after every block consumed the
// previous vintage (true data dependency through the C/dh packets).
//
// out rows double as U storage (gemm output). h(t) is emitted to out row t-3
// through a 3-deep LDS ring (64-col slice per block), so U prefetches (reader
// at step t reads row t) always complete before any writer touches the row.
// ---------------------------------------------------------------------------
__global__ __launch_bounds__(NTHR)
__attribute__((amdgpu_waves_per_eu(2, 2)))
void cwrnn_rec(
    float* __restrict__ out, const float* __restrict__ Whh,
    unsigned long long* __restrict__ comm)
{
    const int tid   = threadIdx.x;
    const int b     = blockIdx.x;        // 0..31
    const int lane  = tid & 63;
    const int wave  = tid >> 6;          // 0..7
    const int r8    = tid >> 4;          // row group: rows 8*r8..8*r8+7
    const int c16   = tid & 15;          // col group: cols 16*c16..16*c16+15
    const int rsel  = c16 & 7;
    const int myrow = 8 * r8 + rsel;     // row this thread finalizes (c16<8)

    unsigned long long* comm_h = comm;            // [7*256] rest-row packets
    unsigned long long* comm_c = comm + 7 * MOD;  // [256]   C packets

    __shared__ __align__(16) float lds_h[HID];       // replicated full h
    __shared__ __align__(16) float h0p[320];         // padded h0: word = e + (e>>4)*4
    __shared__ __align__(16) float lds_C[MOD];       // replicated C
    __shared__ __align__(16) float lds_delta[7 * MOD];
    __shared__ __align__(16) float lds_u0[MOD];      // U0[t] (prefetched)
    __shared__ __align__(16) float lds_ur[56];       // U[t] for owned rest rows
    __shared__ __align__(16) float lds_ring[3][64];  // delayed out slice

    // ---- W00 fragment in registers: rows 8r8..+7, cols 16c16..+15 (128 VGPR)
    float4 w00[8][4];
#pragma unroll
    for (int rr = 0; rr < 8; ++rr) {
        const float* wr = Whh + (size_t)(8 * r8 + rr) * HID + 16 * c16;
#pragma unroll
        for (int i = 0; i < 4; ++i) w00[rr][i] = *(const float4*)(wr + 4 * i);
    }

    // ---- zero init (h(0) = 0, C(0) = 0)
    for (int i = tid; i < HID; i += NTHR) lds_h[i] = 0.f;
    if (tid < 320) h0p[tid] = 0.f;
    if (tid < MOD) lds_C[tid] = 0.f;
    if (tid < 56)  lds_ur[tid] = 0.f;
    if (tid < 192) (&lds_ring[0][0])[tid] = 0.f;

    {   // preload U(1) = gemm row 0, cols [0,256)
        float4 u4 = make_float4(0.f, 0.f, 0.f, 0.f);
        if (tid < 64) u4 = *(const float4*)(out + 4 * tid);
        __syncthreads();
        if (tid < 64) *(float4*)(lds_u0 + 4 * tid) = u4;
        __syncthreads();
    }

    for (int t = 1; t <= T_STEPS; ++t) {
        const bool ev = (t & 1) == 0;
        const int ctz = __builtin_ctz(t);
        const int j   = ev ? (ctz < 7 ? ctz : 7) : 0;  // active rest modules 1..j
        const unsigned long long tagbits =
            ((unsigned long long)(unsigned)t) << 32;

        // ---------- early phase: U value, delayed emission, U prefetch issue
        const float uval = lds_u0[myrow];
        if (t >= 3 && tid < 16) {   // emit out row t-3 = h(t-2), slot (t+1)%3
            float4 e4 = *(const float4*)(&lds_ring[(t + 1) % 3][4 * tid]);
            *(float4*)(out + (size_t)(t - 3) * HID + 64 * b + 4 * tid) = e4;
        }
        float4 pf0 = make_float4(0.f, 0.f, 0.f, 0.f);
        float4 pfr = make_float4(0.f, 0.f, 0.f, 0.f);
        if (t < T_STEPS) {
            if (tid < 64)   // U0 for step t+1 (gemm row t)
                pf0 = *(const float4*)(out + (size_t)t * HID + 4 * tid);
            if (!ev && tid >= 64 && tid < 78) {  // rest-U for even step t+1
                const int idx = tid - 64, mm = idx >> 1, dd = idx & 1;
                pfr = *(const float4*)(out + (size_t)t * HID
                                       + (mm + 1) * MOD + RPM * b + 4 * dd);
            }
        }

        // ---------- even: owned rest rows (full 2048-dot) + publish
        if (ev) {
            for (int ridx = wave; ridx < RPM * j; ridx += 8) {
                const int m = 1 + (ridx >> 3);
                const int e = ridx & 7;
                const float* wrow = Whh + (size_t)(m * MOD + RPM * b + e) * HID;
                float4 wv[8];
#pragma unroll
                for (int k = 0; k < 8; ++k)
                    wv[k] = *(const float4*)(wrow + 4 * lane + 256 * k);
                float sx = 0.f, sy = 0.f, sz = 0.f, sw = 0.f;
#pragma unroll
                for (int k = 0; k < 8; ++k) {
                    const float4 hv = *(const float4*)(lds_h + 4 * lane + 256 * k);
                    sx = fmaf(wv[k].x, hv.x, sx);
                    sy = fmaf(wv[k].y, hv.y, sy);
                    sz = fmaf(wv[k].z, hv.z, sz);
                    sw = fmaf(wv[k].w, hv.w, sw);
                }
                float acc = (sx + sy) + (sz + sw);
#pragma unroll
                for (int off = 32; off; off >>= 1)
                    acc += __shfl_xor(acc, off, 64);
                if (lane == 0) {
                    const float hv = tanhf(lds_ur[(m - 1) * 8 + e] + acc);
                    agent_store_u64(comm_h + (m - 1) * MOD + RPM * b + e,
                        tagbits | (unsigned long long)__float_as_uint(hv));
                }
            }
        }

        // ---------- issue poll prefetch loads (hidden under the W00 MAC)
        const int nslot = j * MOD;
        unsigned long long hp0 = 0, hp1 = 0, hp2 = 0, hp3 = 0;
        const bool hw0 = ev && (tid < nslot);
        const bool hw1 = ev && (tid + 512 < nslot);
        const bool hw2 = ev && (tid + 1024 < nslot);
        const bool hw3 = ev && (tid + 1536 < nslot);
        unsigned long long cp = 0;
        if (ev) {
            if (hw0) hp0 = agent_load_u64(comm_h + tid);
            if (hw1) hp1 = agent_load_u64(comm_h + tid + 512);
            if (hw2) hp2 = agent_load_u64(comm_h + tid + 1024);
            if (hw3) hp3 = agent_load_u64(comm_h + tid + 1536);
        } else {
            if (tid < MOD) cp = agent_load_u64(comm_c + tid);
        }

        // ---------- module-0 MAC (every step, fully local): W00 . h0(t-1)
        float a[8];
#pragma unroll
        for (int rr = 0; rr < 8; ++rr) a[rr] = 0.f;
#pragma unroll
        for (int i = 0; i < 4; ++i) {
            const float4 hv = *(const float4*)(h0p + 20 * c16 + 4 * i);
#pragma unroll
            for (int rr = 0; rr < 8; ++rr) {
                a[rr] = fmaf(w00[rr][i].x, hv.x, a[rr]);
                a[rr] = fmaf(w00[rr][i].y, hv.y, a[rr]);
                a[rr] = fmaf(w00[rr][i].z, hv.z, a[rr]);
                a[rr] = fmaf(w00[rr][i].w, hv.w, a[rr]);
            }
        }
#pragma unroll
        for (int off = 1; off <= 8; off <<= 1) {
#pragma unroll
            for (int rr = 0; rr < 8; ++rr)
                a[rr] += __shfl_xor(a[rr], off, 64);
        }
        float pre = a[0];                    // static-index select (rule #20)
#pragma unroll
        for (int rr = 1; rr < 8; ++rr) pre = (rsel == rr) ? a[rr] : pre;

        if (!ev) {
            // ---- odd: finish C poll (tag t-1; t=1 passes on memset tags==0)
            if (tid < MOD) {
                const unsigned need = (unsigned)(t - 1);
                while ((unsigned)(cp >> 32) < need)
                    cp = agent_load_u64(comm_c + tid);
            }
            __syncthreads();                                   // A (orders prev dC reads)
            if (tid < MOD) lds_C[tid] = __uint_as_float((unsigned)cp);
            __syncthreads();                                   // A'
            const float hv_new = tanhf(uval + lds_C[myrow] + pre);
            if (c16 < 8) {
                lds_h[myrow] = hv_new;
                h0p[myrow + (myrow >> 4) * 4] = hv_new;
                if (b < 4 && (myrow >> 6) == b)
                    lds_ring[t % 3][myrow & 63] = hv_new;
            }
            if (b >= 4 && tid < 16)   // slice unchanged at odd steps: carry
                *(float4*)(&lds_ring[t % 3][4 * tid]) =
                    *(const float4*)(&lds_ring[(t + 2) % 3][4 * tid]);
            if (t < T_STEPS) {
                if (tid < 64) *(float4*)(lds_u0 + 4 * tid) = pf0;
                if (tid >= 64 && tid < 78) {
                    const int idx = tid - 64;
                    *(float4*)(lds_ur + (idx >> 1) * 8 + 4 * (idx & 1)) = pfr;
                }
            }
            __syncthreads();                                   // B (end)
        } else {
            // ---- even: finish module-0 with the CURRENT C (vintage t-2)
            const float hv_new = tanhf(uval + lds_C[myrow] + pre);
            // ---- finish h-packet poll (tag t), register-only retry
            {
                const unsigned need = (unsigned)t;
                for (;;) {
                    bool ok = (!hw0 || (unsigned)(hp0 >> 32) >= need)
                           && (!hw1 || (unsigned)(hp1 >> 32) >= need)
                           && (!hw2 || (unsigned)(hp2 >> 32) >= need)
                           && (!hw3 || (unsigned)(hp3 >> 32) >= need);
                    if (ok) break;
                    if (hw0) hp0 = agent_load_u64(comm_h + tid);
                    if (hw1) hp1 = agent_load_u64(comm_h + tid + 512);
                    if (hw2) hp2 = agent_load_u64(comm_h + tid + 1024);
                    if (hw3) hp3 = agent_load_u64(comm_h + tid + 1536);
                }
            }
            __syncthreads();                                   // A (all lds_h reads done)
            if (c16 < 8) {
                lds_h[myrow] = hv_new;
                h0p[myrow + (myrow >> 4) * 4] = hv_new;
                if (b < 4 && (myrow >> 6) == b)
                    lds_ring[t % 3][myrow & 63] = hv_new;
            }
            {   // commit polled rest-h values, form deltas, update ring slice
                const int base = 64 * b - MOD;   // slice slot base (b>=4)
                if (hw0) {
                    const float v = __uint_as_float((unsigned)hp0);
                    const int s = tid;
                    lds_delta[s] = v - lds_h[MOD + s];
                    lds_h[MOD + s] = v;
                    if (b >= 4 && s >= base && s < base + 64)
                        lds_ring[t % 3][s - base] = v;
                }
                if (hw1) {
                    const float v = __uint_as_float((unsigned)hp1);
                    const int s = tid + 512;
                    lds_delta[s] = v - lds_h[MOD + s];
                    lds_h[MOD + s] = v;
                    if (b >= 4 && s >= base && s < base + 64)
                        lds_ring[t % 3][s - base] = v;
                }
                if (hw2) {
                    const float v = __uint_as_float((unsigned)hp2);
                    const int s = tid + 1024;
                    lds_delta[s] = v - lds_h[MOD + s];
                    lds_h[MOD + s] = v;
                    if (b >= 4 && s >= base && s < base + 64)
                        lds_ring[t % 3][s - base] = v;
                }
                if (hw3) {
                    const float v = __uint_as_float((unsigned)hp3);
                    const int s = tid + 1536;
                    lds_delta[s] = v - lds_h[MOD + s];
                    lds_h[MOD + s] = v;
                    if (b >= 4 && s >= base && s < base + 64)
                        lds_ring[t % 3][s - base] = v;
                }
            }
            if (b >= 4 && (b >> 2) > j && tid < 16)  // slice module inactive
                *(float4*)(&lds_ring[t % 3][4 * tid]) =
                    *(const float4*)(&lds_ring[(t + 2) % 3][4 * tid]);
            if (t < T_STEPS && tid < 64)
                *(float4*)(lds_u0 + 4 * tid) = pf0;
            __syncthreads();                                   // B
            // ---- owned dC entry (one wave per entry) + publish (tag t).
            // Safe without a trailing barrier: lds_C[gi] is re-written only at
            // the next odd step by thread gi, whose comm_c poll cannot succeed
            // until THIS store lands (self-synchronizing through the packet).
            {
                const float* wc = Whh + (size_t)(NCE * b + wave) * HID + MOD;
                float acc = 0.f;
                for (int k0 = 0; k0 < nslot; k0 += 256) {
                    const float w0_ = wc[k0 + lane];
                    const float w1_ = wc[k0 + lane + 64];
                    const float w2_ = wc[k0 + lane + 128];
                    const float w3_ = wc[k0 + lane + 192];
                    acc = fmaf(w0_, lds_delta[k0 + lane], acc);
                    acc = fmaf(w1_, lds_delta[k0 + lane + 64], acc);
                    acc = fmaf(w2_, lds_delta[k0 + lane + 128], acc);
                    acc = fmaf(w3_, lds_delta[k0 + lane + 192], acc);
                }
#pragma unroll
                for (int off = 32; off; off >>= 1)
                    acc += __shfl_xor(acc, off, 64);
                if (lane == 0) {
                    const int gi = NCE * b + wave;
                    const float cn = lds_C[gi] + acc;
                    agent_store_u64(comm_c + gi,
                        tagbits | (unsigned long long)__float_as_uint(cn));
                }
            }
        }
    }

    // ---- flush the last two delayed rows: h(T-1) -> row T-2, h(T) -> row T-1
    __syncthreads();
    if (tid < 16) {
        *(float4*)(out + (size_t)(T_STEPS - 2) * HID + 64 * b + 4 * tid) =
            *(const float4*)(&lds_ring[(T_STEPS - 1) % 3][4 * tid]);
        *(float4*)(out + (size_t)(T_STEPS - 1) * HID + 64 * b + 4 * tid) =
            *(const float4*)(&lds_ring[T_STEPS % 3][4 * tid]);
    }
}

// ---------------------------------------------------------------------------
extern "C" void kernel_launch(void* const* d_in, const int* in_sizes, int n_in,
                              void* d_out, int out_size, void* d_ws, size_t ws_size,
                              hipStream_t stream) {
    const float* x   = (const float*)d_in[0];
    const float* Wih = (const float*)d_in[1];
    const float* Whh = (const float*)d_in[2];
    const float* bih = (const float*)d_in[3];
    const float* bhh = (const float*)d_in[4];
    float* out = (float*)d_out;
    unsigned long long* comm = (unsigned long long*)d_ws;

    // packet tags must start at 0 (t runs 1..4096): (1792 + 256) x 8B = 16 KB
    hipMemsetAsync(d_ws, 0, (7 * MOD + MOD) * sizeof(unsigned long long), stream);

    dim3 g1(HID / BN, T_STEPS / BM);        // (16, 32)
    gemm_u<<<g1, 256, 0, stream>>>(x, Wih, bih, bhh, out);
    cwrnn_rec<<<NBLK, NTHR, 0, stream>>>(out, Whh, comm);
}